// Round 1
// baseline (768.795 us; speedup 1.0000x reference)
//
#include <hip/hip_runtime.h>
#include <hip/hip_bf16.h>

// Qriaffine: out[n,i,j] = sum_{a,b,c,d} l1[n,i,a] W[a,b,c,d] l2[n,j,b] h1[n,i,c] h2[n,j,d]
//   (l1/l2 are layer1/layer2 with a bias-1 appended -> 65 wide)
// Plan:
//   P[(n,i)][(a*65+c)] = l1[a]*h1[c]        (8192 x 4225, bf16, pad K->4256)
//   Wt2[(b*65+d)][(a*65+c)] = W[a,b,c,d]    (4225 x 4225, bf16, pad -> 4352 x 4256)
//   Q = P @ Wt2^T-form (NT gemm)            (8192 x 4352, bf16)
//   R[(n,j)][(b*65+d)] = l2[b]*h2[d]        (8192 x 4352, bf16, zero pad cols)
//   out_n = Q_n @ R_n^T (NT gemm, f32 out)  (8 x 1024 x 1024)

typedef __attribute__((ext_vector_type(8))) short short8;   // 8 bf16 = 4 VGPRs
typedef __attribute__((ext_vector_type(4))) float floatx4;  // MFMA 16x16 acc

#define KP 4256   // padded (a,c) dim: 133*32
#define DP 4352   // padded (b,d) dim: 34*128
#define NROW 8192 // n*L

// ---------------- zero helper (16B granularity) ----------------
__global__ void zero_kernel(float4* __restrict__ p, long n) {
  long i = (long)blockIdx.x * blockDim.x + threadIdx.x;
  long stride = (long)gridDim.x * blockDim.x;
  float4 z = make_float4(0.f, 0.f, 0.f, 0.f);
  for (; i < n; i += stride) p[i] = z;
}

// ---------------- W[a,b,c,d] -> Wt2[(b*65+d)][(a*65+c)] (bf16) ----------------
__global__ void build_wt2(const float* __restrict__ W, __hip_bfloat16* __restrict__ Wt2) {
  __shared__ __hip_bfloat16 tile[65 * 66];
  const int a = blockIdx.x, b = blockIdx.y;
  const float* src = W + (size_t)(a * 65 + b) * 4225;  // contiguous (c,d) plane
  for (int idx = threadIdx.x; idx < 4225; idx += 256) {
    int c = idx / 65, d = idx - c * 65;
    tile[d * 66 + c] = __float2bfloat16(src[idx]);
  }
  __syncthreads();
  for (int idx = threadIdx.x; idx < 4225; idx += 256) {
    int d = idx / 65, c = idx - d * 65;
    Wt2[(size_t)(b * 65 + d) * KP + a * 65 + c] = tile[d * 66 + c];
  }
}

// ---------------- P/R builder: P[row][x*65+y] = layer_row[x] * h_row[y] ----------------
// layer is (row,64), bias 1.0 appended as x==64; h is (row,65). width = KP or DP.
__global__ void build_p(const float* __restrict__ layer, const float* __restrict__ h,
                        __hip_bfloat16* __restrict__ P, int width) {
  const int row = blockIdx.x;
  __shared__ float lv[65], hv[65];
  if (threadIdx.x < 64) lv[threadIdx.x] = layer[(size_t)row * 64 + threadIdx.x];
  if (threadIdx.x == 64) lv[64] = 1.0f;
  if (threadIdx.x < 65) hv[threadIdx.x] = h[(size_t)row * 65 + threadIdx.x];
  __syncthreads();
  for (int idx = threadIdx.x; idx < width; idx += 256) {
    float v = 0.f;
    if (idx < 4225) {
      int x = idx / 65, y = idx - x * 65;
      v = lv[x] * hv[y];
    }
    P[(size_t)row * width + idx] = __float2bfloat16(v);
  }
}

// ---------------- NT GEMM: C[i][j] = sum_k A[i][k]*B[j][k] ----------------
// A: M x K (lda), B: N x K (ldb), both row-major bf16 -> all K-contiguous loads.
// 128x128 block tile, 4 waves of 64x64, BK=32, mfma_f32_16x16x32_bf16.
template <int STORE_BF16>
__global__ __launch_bounds__(256) void gemm_nt(
    const __hip_bfloat16* __restrict__ A, const __hip_bfloat16* __restrict__ B,
    void* __restrict__ Cv, int K, int lda, int ldb, int ldc,
    long sA, long sB, long sC) {
  __shared__ __hip_bfloat16 As[128 * 40];  // stride 40: 2-way bank alias (free)
  __shared__ __hip_bfloat16 Bs[128 * 40];
  const int z = blockIdx.z;
  A += (long)z * sA;
  B += (long)z * sB;
  const int bm = blockIdx.y * 128;
  const int bn = blockIdx.x * 128;
  const int t = threadIdx.x;
  const int lane = t & 63;
  const int wave = t >> 6;
  const int quad = lane >> 4;   // k-group of the MFMA fragment
  const int lrow = lane & 15;   // m (A) / n (B) index within 16-tile
  const int wm = (wave >> 1) * 64;
  const int wn = (wave & 1) * 64;
  const int koff = quad * 8;

  // staging: 512 chunks of 8 bf16 per 128x32 tile; thread t does chunks t, t+256
  const int r0 = t >> 2;
  const int s0 = (t & 3) * 8;

  floatx4 acc[4][4] = {};

  for (int k0 = 0; k0 < K; k0 += 32) {
    const float4 av0 = *(const float4*)(A + (size_t)(bm + r0) * lda + k0 + s0);
    const float4 av1 = *(const float4*)(A + (size_t)(bm + r0 + 64) * lda + k0 + s0);
    const float4 bv0 = *(const float4*)(B + (size_t)(bn + r0) * ldb + k0 + s0);
    const float4 bv1 = *(const float4*)(B + (size_t)(bn + r0 + 64) * ldb + k0 + s0);
    __syncthreads();  // previous iter's LDS reads done
    *(float4*)(&As[r0 * 40 + s0]) = av0;
    *(float4*)(&As[(r0 + 64) * 40 + s0]) = av1;
    *(float4*)(&Bs[r0 * 40 + s0]) = bv0;
    *(float4*)(&Bs[(r0 + 64) * 40 + s0]) = bv1;
    __syncthreads();

    short8 af[4], bf[4];
#pragma unroll
    for (int i = 0; i < 4; ++i) {
      af[i] = *(const short8*)(&As[(wm + i * 16 + lrow) * 40 + koff]);
      bf[i] = *(const short8*)(&Bs[(wn + i * 16 + lrow) * 40 + koff]);
    }
#pragma unroll
    for (int mi = 0; mi < 4; ++mi)
#pragma unroll
      for (int nj = 0; nj < 4; ++nj)
        acc[mi][nj] = __builtin_amdgcn_mfma_f32_16x16x32_bf16(af[mi], bf[nj], acc[mi][nj], 0, 0, 0);
  }

  // C/D layout (verified m89/m91): col = lane&15, row = quad*4 + reg
  if (STORE_BF16) {
    __hip_bfloat16* C = (__hip_bfloat16*)Cv + (long)z * sC;
#pragma unroll
    for (int mi = 0; mi < 4; ++mi)
#pragma unroll
      for (int nj = 0; nj < 4; ++nj)
#pragma unroll
        for (int r = 0; r < 4; ++r) {
          int row = bm + wm + mi * 16 + quad * 4 + r;
          int col = bn + wn + nj * 16 + lrow;
          C[(size_t)row * ldc + col] = __float2bfloat16(acc[mi][nj][r]);
        }
  } else {
    float* C = (float*)Cv + (long)z * sC;
#pragma unroll
    for (int mi = 0; mi < 4; ++mi)
#pragma unroll
      for (int nj = 0; nj < 4; ++nj)
#pragma unroll
        for (int r = 0; r < 4; ++r) {
          int row = bm + wm + mi * 16 + quad * 4 + r;
          int col = bn + wn + nj * 16 + lrow;
          C[(size_t)row * ldc + col] = acc[mi][nj][r];
        }
  }
}

extern "C" void kernel_launch(void* const* d_in, const int* in_sizes, int n_in,
                              void* d_out, int out_size, void* d_ws, size_t ws_size,
                              hipStream_t stream) {
  const float* layer1 = (const float*)d_in[0];
  const float* layer2 = (const float*)d_in[1];
  const float* h1 = (const float*)d_in[3];
  const float* h2 = (const float*)d_in[4];
  const float* W = (const float*)d_in[6];
  float* out = (float*)d_out;

  // workspace layout (bytes): P | Wt2 | Q | R  = 249,380,864 total
  char* ws = (char*)d_ws;
  __hip_bfloat16* P = (__hip_bfloat16*)(ws);                      // 8192*4256*2 = 69,730,304
  __hip_bfloat16* Wt2 = (__hip_bfloat16*)(ws + 69730304ULL);      // 4352*4256*2 = 37,044,224
  __hip_bfloat16* Q = (__hip_bfloat16*)(ws + 106774528ULL);       // 8192*4352*2 = 71,303,168
  __hip_bfloat16* R = (__hip_bfloat16*)(ws + 178077696ULL);       // 8192*4352*2

  // 1) zero Wt2 (covers pad rows/cols; real entries overwritten next)
  zero_kernel<<<2048, 256, 0, stream>>>((float4*)Wt2, (long)DP * KP * 2 / 16);
  // 2) transpose+cast W
  build_wt2<<<dim3(65, 65), 256, 0, stream>>>(W, Wt2);
  // 3) P and R
  build_p<<<NROW, 256, 0, stream>>>(layer1, h1, P, KP);
  build_p<<<NROW, 256, 0, stream>>>(layer2, h2, R, DP);
  // 4) Q = P @ Wt2 (NT): M=8192, N=4352, K=4256
  gemm_nt<1><<<dim3(DP / 128, NROW / 128, 1), 256, 0, stream>>>(
      P, Wt2, Q, KP, KP, KP, DP, 0, 0, 0);
  // 5) out_n = Q_n @ R_n^T: M=N=1024, K=4352, batched over n=8
  gemm_nt<0><<<dim3(1024 / 128, 1024 / 128, 8), 256, 0, stream>>>(
      Q, R, out, DP, DP, DP, 1024, 1024L * DP, 1024L * DP, 1024L * 1024);
}

// Round 2
// 692.453 us; speedup vs baseline: 1.1102x; 1.1102x over previous
//
#include <hip/hip_runtime.h>
#include <hip/hip_bf16.h>

// Qriaffine: out[n,i,j] = sum_{a,b,c,d} l1[n,i,a] W[a,b,c,d] l2[n,j,b] h1[n,i,c] h2[n,j,d]
// Plan:
//   P[(n,i)][(a*65+c)] = l1[a]*h1[c]        (8192 x 4225, bf16, pad K->4256)
//   Wt2[(b*65+d)][(a*65+c)] = W[a,b,c,d]    (4225 x 4225, bf16, pad -> 4352 x 4256)
//   Q = P @ Wt2 (NT gemm)                   (8192 x 4352, bf16)
//   R[(n,j)][(b*65+d)] = l2[b]*h2[d]        (8192 x 4352, bf16, zero pad cols)
//   out_n = Q_n @ R_n^T (NT gemm, f32 out)  (8 x 1024 x 1024)
//
// R2: global_load_lds width=16 staging + XOR-swizzled LDS (conflict-free
// ds_read_b128) + vectorized build_p stores.

typedef __attribute__((ext_vector_type(8))) short short8;   // 8 bf16 = 4 VGPRs
typedef __attribute__((ext_vector_type(4))) float floatx4;  // MFMA 16x16 acc

#define KP 4256   // padded (a,c) dim: 133*32
#define DP 4352   // padded (b,d) dim: 34*128
#define NROW 8192 // n*L

__device__ __forceinline__ void async_ld16(const void* g, void* l) {
  __builtin_amdgcn_global_load_lds(
      (const __attribute__((address_space(1))) unsigned int*)g,
      (__attribute__((address_space(3))) unsigned int*)l, 16, 0, 0);
}

// ---------------- zero helper (16B granularity) ----------------
__global__ void zero_kernel(float4* __restrict__ p, long n) {
  long i = (long)blockIdx.x * blockDim.x + threadIdx.x;
  long stride = (long)gridDim.x * blockDim.x;
  float4 z = make_float4(0.f, 0.f, 0.f, 0.f);
  for (; i < n; i += stride) p[i] = z;
}

// ---------------- W[a,b,c,d] -> Wt2[(b*65+d)][(a*65+c)] (bf16) ----------------
__global__ void build_wt2(const float* __restrict__ W, __hip_bfloat16* __restrict__ Wt2) {
  __shared__ __hip_bfloat16 tile[65 * 66];
  const int a = blockIdx.x, b = blockIdx.y;
  const float* src = W + (size_t)(a * 65 + b) * 4225;  // contiguous (c,d) plane
  for (int idx = threadIdx.x; idx < 4225; idx += 256) {
    int c = idx / 65, d = idx - c * 65;
    tile[d * 66 + c] = __float2bfloat16(src[idx]);
  }
  __syncthreads();
  for (int idx = threadIdx.x; idx < 4225; idx += 256) {
    int d = idx / 65, c = idx - d * 65;
    Wt2[(size_t)(b * 65 + d) * KP + a * 65 + c] = tile[d * 66 + c];
  }
}

// ---------------- P/R builder: P[row][x*65+y] = layer_row[x] * h_row[y] ----------------
// layer is (row,64), bias 1.0 appended as x==64; h is (row,65). width = KP or DP.
__global__ void build_p(const float* __restrict__ layer, const float* __restrict__ h,
                        __hip_bfloat16* __restrict__ P, int width) {
  const int row = blockIdx.x;
  __shared__ float lv[65], hv[65];
  if (threadIdx.x < 64) lv[threadIdx.x] = layer[(size_t)row * 64 + threadIdx.x];
  if (threadIdx.x == 64) lv[64] = 1.0f;
  if (threadIdx.x < 65) hv[threadIdx.x] = h[(size_t)row * 65 + threadIdx.x];
  __syncthreads();
  for (int base = threadIdx.x * 8; base < width; base += 256 * 8) {
    alignas(16) __hip_bfloat16 tmp[8];
#pragma unroll
    for (int j = 0; j < 8; ++j) {
      int idx = base + j;
      float v = 0.f;
      if (idx < 4225) {
        int x = idx / 65, y = idx - x * 65;
        v = lv[x] * hv[y];
      }
      tmp[j] = __float2bfloat16(v);
    }
    *(float4*)(P + (size_t)row * width + base) = *(const float4*)tmp;
  }
}

// ---------------- NT GEMM: C[i][j] = sum_k A[i][k]*B[j][k] ----------------
// A: M x K (lda), B: N x K (ldb), row-major bf16. 128x128 block tile, 4 waves
// of 64x64, BK=32, mfma_f32_16x16x32_bf16. Staging via global_load_lds x16.
// LDS layout XOR-swizzled: cell (row, sl) holds k-group sg = sl ^ (row&3),
// making fragment ds_read_b128 bank-balanced (8 accesses/bank/wave = minimum).
template <int STORE_BF16>
__global__ __launch_bounds__(256) void gemm_nt(
    const __hip_bfloat16* __restrict__ A, const __hip_bfloat16* __restrict__ B,
    void* __restrict__ Cv, int K, int lda, int ldb, int ldc,
    long sA, long sB, long sC) {
  __shared__ alignas(16) __hip_bfloat16 As[128 * 32];
  __shared__ alignas(16) __hip_bfloat16 Bs[128 * 32];
  const int z = blockIdx.z;
  A += (long)z * sA;
  B += (long)z * sB;
  const int bm = blockIdx.y * 128;
  const int bn = blockIdx.x * 128;
  const int t = threadIdx.x;
  const int lane = t & 63;
  const int wave = t >> 6;
  const int quad = lane >> 4;   // k-group of the MFMA fragment
  const int lrow = lane & 15;   // m (A) / n (B) index within 16-tile
  const int wm = (wave >> 1) * 64;
  const int wn = (wave & 1) * 64;

  // staging: 512 16B-chunks per 128x32 tile. Chunk L -> LDS cell (row=L>>2,
  // sl=L&3) holding global k-group sg = sl ^ (row&3). Thread t handles
  // L0 = t (round 0) and L1 = t+256 (round 1); DMA dest is wave-uniform
  // base + lane*16, so round-r wave-w base = chunk (r*256 + w*64).
  const int L0 = t, L1 = t + 256;
  const int r0 = L0 >> 2, sg0 = (L0 & 3) ^ (r0 & 3);
  const int r1 = L1 >> 2, sg1 = (L1 & 3) ^ (r1 & 3);
  const __hip_bfloat16* ga0 = A + (size_t)(bm + r0) * lda + sg0 * 8;
  const __hip_bfloat16* ga1 = A + (size_t)(bm + r1) * lda + sg1 * 8;
  const __hip_bfloat16* gb0 = B + (size_t)(bn + r0) * ldb + sg0 * 8;
  const __hip_bfloat16* gb1 = B + (size_t)(bn + r1) * ldb + sg1 * 8;
  __hip_bfloat16* lA0 = As + (size_t)(wave * 64) * 8;
  __hip_bfloat16* lA1 = As + (size_t)(256 + wave * 64) * 8;
  __hip_bfloat16* lB0 = Bs + (size_t)(wave * 64) * 8;
  __hip_bfloat16* lB1 = Bs + (size_t)(256 + wave * 64) * 8;

  // fragment read column: sl = quad ^ (lrow&3)  (row&3 == lrow&3 since wm,
  // wn, i*16 are multiples of 16)
  const int slq = (quad ^ (lrow & 3)) * 8;

  floatx4 acc[4][4] = {};

  for (int k0 = 0; k0 < K; k0 += 32) {
    __syncthreads();  // previous iter's LDS reads done
    async_ld16(ga0 + k0, lA0);
    async_ld16(ga1 + k0, lA1);
    async_ld16(gb0 + k0, lB0);
    async_ld16(gb1 + k0, lB1);
    __syncthreads();  // drains vmcnt -> tiles resident in LDS

    short8 af[4], bf[4];
#pragma unroll
    for (int i = 0; i < 4; ++i) {
      af[i] = *(const short8*)(&As[(wm + i * 16 + lrow) * 32 + slq]);
      bf[i] = *(const short8*)(&Bs[(wn + i * 16 + lrow) * 32 + slq]);
    }
#pragma unroll
    for (int mi = 0; mi < 4; ++mi)
#pragma unroll
      for (int nj = 0; nj < 4; ++nj)
        acc[mi][nj] = __builtin_amdgcn_mfma_f32_16x16x32_bf16(af[mi], bf[nj], acc[mi][nj], 0, 0, 0);
  }

  // C/D layout (verified m89/m91): col = lane&15, row = quad*4 + reg
  if (STORE_BF16) {
    __hip_bfloat16* C = (__hip_bfloat16*)Cv + (long)z * sC;
#pragma unroll
    for (int mi = 0; mi < 4; ++mi)
#pragma unroll
      for (int nj = 0; nj < 4; ++nj)
#pragma unroll
        for (int r = 0; r < 4; ++r) {
          int row = bm + wm + mi * 16 + quad * 4 + r;
          int col = bn + wn + nj * 16 + lrow;
          C[(size_t)row * ldc + col] = __float2bfloat16(acc[mi][nj][r]);
        }
  } else {
    float* C = (float*)Cv + (long)z * sC;
#pragma unroll
    for (int mi = 0; mi < 4; ++mi)
#pragma unroll
      for (int nj = 0; nj < 4; ++nj)
#pragma unroll
        for (int r = 0; r < 4; ++r) {
          int row = bm + wm + mi * 16 + quad * 4 + r;
          int col = bn + wn + nj * 16 + lrow;
          C[(size_t)row * ldc + col] = acc[mi][nj][r];
        }
  }
}

extern "C" void kernel_launch(void* const* d_in, const int* in_sizes, int n_in,
                              void* d_out, int out_size, void* d_ws, size_t ws_size,
                              hipStream_t stream) {
  const float* layer1 = (const float*)d_in[0];
  const float* layer2 = (const float*)d_in[1];
  const float* h1 = (const float*)d_in[3];
  const float* h2 = (const float*)d_in[4];
  const float* W = (const float*)d_in[6];
  float* out = (float*)d_out;

  // workspace layout (bytes): P | Wt2 | Q | R  = 249,380,864 total
  char* ws = (char*)d_ws;
  __hip_bfloat16* P = (__hip_bfloat16*)(ws);                      // 8192*4256*2 = 69,730,304
  __hip_bfloat16* Wt2 = (__hip_bfloat16*)(ws + 69730304ULL);      // 4352*4256*2 = 37,044,224
  __hip_bfloat16* Q = (__hip_bfloat16*)(ws + 106774528ULL);       // 8192*4352*2 = 71,303,168
  __hip_bfloat16* R = (__hip_bfloat16*)(ws + 178077696ULL);       // 8192*4352*2

  // 1) zero Wt2 (covers pad rows/cols; real entries overwritten next)
  zero_kernel<<<2048, 256, 0, stream>>>((float4*)Wt2, (long)DP * KP * 2 / 16);
  // 2) transpose+cast W
  build_wt2<<<dim3(65, 65), 256, 0, stream>>>(W, Wt2);
  // 3) P and R
  build_p<<<NROW, 256, 0, stream>>>(layer1, h1, P, KP);
  build_p<<<NROW, 256, 0, stream>>>(layer2, h2, R, DP);
  // 4) Q = P @ Wt2 (NT): M=8192, N=4352, K=4256
  gemm_nt<1><<<dim3(DP / 128, NROW / 128, 1), 256, 0, stream>>>(
      P, Wt2, Q, KP, KP, KP, DP, 0, 0, 0);
  // 5) out_n = Q_n @ R_n^T: M=N=1024, K=4352, batched over n=8
  gemm_nt<0><<<dim3(1024 / 128, 1024 / 128, 8), 256, 0, stream>>>(
      Q, R, out, DP, DP, DP, 1024, 1024L * DP, 1024L * DP, 1024L * 1024);
}

// Round 3
// 612.147 us; speedup vs baseline: 1.2559x; 1.1312x over previous
//
#include <hip/hip_runtime.h>
#include <hip/hip_bf16.h>

// Qriaffine: out[n,i,j] = sum_{a,b,c,d} l1[n,i,a] W[a,b,c,d] l2[n,j,b] h1[n,i,c] h2[n,j,d]
// Plan:
//   P[(n,i)][(a*65+c)] = l1[a]*h1[c]        (8192 x 4225, bf16, pad K->4288)
//   Wt2[(b*65+d)][(a*65+c)] = W[a,b,c,d]    (4225 x 4225, bf16, pad -> 4352 x 4288)
//   Q = P @ Wt2 (NT gemm)                   (8192 x 4352, bf16)
//   R[(n,j)][(b*65+d)] = l2[b]*h2[d]        (8192 x 4352, bf16, built AFTER gemm1,
//                                            reusing the P/Wt2 region)
//   out_n = Q_n @ R_n^T (NT gemm, f32 out)  (8 x 1024 x 1024)
//
// R3: BK=64 (half the barrier drains), 32x32x16 MFMA (17% less MFMA-pipe busy,
// half the issue slots), XOR-swizzled LDS chunk^(row&7) -> conflict-free
// ds_read_b128 and DMA writes. global_load_lds width=16 staging kept.

typedef __attribute__((ext_vector_type(8))) short short8;     // 8 bf16 = 4 VGPRs
typedef __attribute__((ext_vector_type(16))) float floatx16;  // MFMA 32x32 acc

#define KP 4288   // padded (a,c) dim: 67*64
#define DP 4352   // padded (b,d) dim: 68*64 = 34*128
#define NROW 8192 // n*L

__device__ __forceinline__ void async_ld16(const void* g, void* l) {
  __builtin_amdgcn_global_load_lds(
      (const __attribute__((address_space(1))) unsigned int*)g,
      (__attribute__((address_space(3))) unsigned int*)l, 16, 0, 0);
}

// ---------------- zero helper (16B granularity) ----------------
__global__ void zero_kernel(float4* __restrict__ p, long n) {
  long i = (long)blockIdx.x * blockDim.x + threadIdx.x;
  long stride = (long)gridDim.x * blockDim.x;
  float4 z = make_float4(0.f, 0.f, 0.f, 0.f);
  for (; i < n; i += stride) p[i] = z;
}

// ---------------- W[a,b,c,d] -> Wt2[(b*65+d)][(a*65+c)] (bf16) ----------------
__global__ void build_wt2(const float* __restrict__ W, __hip_bfloat16* __restrict__ Wt2) {
  __shared__ __hip_bfloat16 tile[65 * 66];
  const int a = blockIdx.x, b = blockIdx.y;
  const float* src = W + (size_t)(a * 65 + b) * 4225;  // contiguous (c,d) plane
  for (int idx = threadIdx.x; idx < 4225; idx += 256) {
    int c = idx / 65, d = idx - c * 65;
    tile[d * 66 + c] = __float2bfloat16(src[idx]);
  }
  __syncthreads();
  for (int idx = threadIdx.x; idx < 4225; idx += 256) {
    int d = idx / 65, c = idx - d * 65;
    Wt2[(size_t)(b * 65 + d) * KP + a * 65 + c] = tile[d * 66 + c];
  }
}

// ---------------- P/R builder: P[row][x*65+y] = layer_row[x] * h_row[y] ----------------
__global__ void build_p(const float* __restrict__ layer, const float* __restrict__ h,
                        __hip_bfloat16* __restrict__ P, int width) {
  const int row = blockIdx.x;
  __shared__ float lv[65], hv[65];
  if (threadIdx.x < 64) lv[threadIdx.x] = layer[(size_t)row * 64 + threadIdx.x];
  if (threadIdx.x == 64) lv[64] = 1.0f;
  if (threadIdx.x < 65) hv[threadIdx.x] = h[(size_t)row * 65 + threadIdx.x];
  __syncthreads();
  for (int base = threadIdx.x * 8; base < width; base += 256 * 8) {
    alignas(16) __hip_bfloat16 tmp[8];
#pragma unroll
    for (int j = 0; j < 8; ++j) {
      int idx = base + j;
      float v = 0.f;
      if (idx < 4225) {
        int x = idx / 65, y = idx - x * 65;
        v = lv[x] * hv[y];
      }
      tmp[j] = __float2bfloat16(v);
    }
    *(float4*)(P + (size_t)row * width + base) = *(const float4*)tmp;
  }
}

// ---------------- NT GEMM: C[i][j] = sum_k A[i][k]*B[j][k] ----------------
// A: M x K (lda), B: N x K (ldb), row-major bf16, K % 64 == 0.
// 128x128 block tile, 4 waves each 64x64 = 2x2 tiles of 32x32, BK=64,
// mfma_f32_32x32x16_bf16. Staging via global_load_lds x16.
// LDS tile 128 rows x 64 bf16 (128 B row = exact bank wrap), stored
// XOR-swizzled: 16B chunk sl of row r holds global k-chunk sl^(r&7).
// -> DMA writes (contiguous 1KB/wave) and fragment ds_read_b128 both hit
// each bank exactly 8x per wave (the minimum).
template <int STORE_BF16>
__global__ __launch_bounds__(256) void gemm_nt(
    const __hip_bfloat16* __restrict__ A, const __hip_bfloat16* __restrict__ B,
    void* __restrict__ Cv, int K, int lda, int ldb, int ldc,
    long sA, long sB, long sC) {
  __shared__ alignas(16) __hip_bfloat16 As[128 * 64];
  __shared__ alignas(16) __hip_bfloat16 Bs[128 * 64];
  const int z = blockIdx.z;
  A += (long)z * sA;
  B += (long)z * sB;
  const int bm = blockIdx.y * 128;
  const int bn = blockIdx.x * 128;
  const int t = threadIdx.x;
  const int lane = t & 63;
  const int wave = t >> 6;
  const int l31 = lane & 31;
  const int lhi = lane >> 5;       // k-half of the 32x32 fragment
  const int wm = (wave >> 1) * 64;
  const int wn = (wave & 1) * 64;

  // ---- DMA staging: 1024 16B-chunks per 128x64 tile, 4 rounds of 256.
  // Chunk L -> LDS byte L*16, i.e. cell (row=L>>3, sl=L&7), holding global
  // k-chunk sg = sl ^ (row&7). Wave-round base is wave-uniform; lane adds
  // lane*16 (DMA constraint).
  const __hip_bfloat16* gA[4];
  const __hip_bfloat16* gB[4];
  __hip_bfloat16* lA[4];
  __hip_bfloat16* lB[4];
#pragma unroll
  for (int r = 0; r < 4; ++r) {
    int L = r * 256 + t;
    int row = L >> 3, sl = L & 7;
    int sg = sl ^ (row & 7);
    gA[r] = A + (size_t)(bm + row) * lda + sg * 8;
    gB[r] = B + (size_t)(bn + row) * ldb + sg * 8;
    lA[r] = As + (size_t)(r * 256 + wave * 64) * 8;
    lB[r] = Bs + (size_t)(r * 256 + wave * 64) * 8;
  }

  // ---- fragment addresses: row r in tile, k-chunk kc -> LDS chunk kc^(r&7).
  // r&7 == l31&7 here (wm, mt*32 are multiples of 32).
  const int x7 = l31 & 7;
  const int rA0 = (wm + l31) * 64, rA1 = (wm + 32 + l31) * 64;
  const int rB0 = (wn + l31) * 64, rB1 = (wn + 32 + l31) * 64;

  floatx16 acc[2][2] = {};

  for (int k0 = 0; k0 < K; k0 += 64) {
    __syncthreads();  // previous iter's LDS reads done
#pragma unroll
    for (int r = 0; r < 4; ++r) {
      async_ld16(gA[r] + k0, lA[r]);
      async_ld16(gB[r] + k0, lB[r]);
    }
    __syncthreads();  // drains vmcnt -> tiles resident in LDS

#pragma unroll
    for (int ks = 0; ks < 4; ++ks) {
      const int pc = ((ks * 2 + lhi) ^ x7) * 8;  // swizzled chunk -> element off
      short8 a0 = *(const short8*)(&As[rA0 + pc]);
      short8 a1 = *(const short8*)(&As[rA1 + pc]);
      short8 b0 = *(const short8*)(&Bs[rB0 + pc]);
      short8 b1 = *(const short8*)(&Bs[rB1 + pc]);
      acc[0][0] = __builtin_amdgcn_mfma_f32_32x32x16_bf16(a0, b0, acc[0][0], 0, 0, 0);
      acc[0][1] = __builtin_amdgcn_mfma_f32_32x32x16_bf16(a0, b1, acc[0][1], 0, 0, 0);
      acc[1][0] = __builtin_amdgcn_mfma_f32_32x32x16_bf16(a1, b0, acc[1][0], 0, 0, 0);
      acc[1][1] = __builtin_amdgcn_mfma_f32_32x32x16_bf16(a1, b1, acc[1][1], 0, 0, 0);
    }
  }

  // C/D layout (verified m74/m101): col = lane&31,
  // row = (reg&3) + 8*(reg>>2) + 4*(lane>>5)
  if (STORE_BF16) {
    __hip_bfloat16* C = (__hip_bfloat16*)Cv + (long)z * sC;
#pragma unroll
    for (int mt = 0; mt < 2; ++mt)
#pragma unroll
      for (int nt = 0; nt < 2; ++nt)
#pragma unroll
        for (int reg = 0; reg < 16; ++reg) {
          int row = bm + wm + mt * 32 + (reg & 3) + 8 * (reg >> 2) + 4 * lhi;
          int col = bn + wn + nt * 32 + l31;
          C[(size_t)row * ldc + col] = __float2bfloat16(acc[mt][nt][reg]);
        }
  } else {
    float* C = (float*)Cv + (long)z * sC;
#pragma unroll
    for (int mt = 0; mt < 2; ++mt)
#pragma unroll
      for (int nt = 0; nt < 2; ++nt)
#pragma unroll
        for (int reg = 0; reg < 16; ++reg) {
          int row = bm + wm + mt * 32 + (reg & 3) + 8 * (reg >> 2) + 4 * lhi;
          int col = bn + wn + nt * 32 + l31;
          C[(size_t)row * ldc + col] = acc[mt][nt][reg];
        }
  }
}

extern "C" void kernel_launch(void* const* d_in, const int* in_sizes, int n_in,
                              void* d_out, int out_size, void* d_ws, size_t ws_size,
                              hipStream_t stream) {
  const float* layer1 = (const float*)d_in[0];
  const float* layer2 = (const float*)d_in[1];
  const float* h1 = (const float*)d_in[3];
  const float* h2 = (const float*)d_in[4];
  const float* W = (const float*)d_in[6];
  float* out = (float*)d_out;

  // workspace layout (bytes), total high-water 178,880,512:
  //   [0 .. 70,254,592)            P  (8192*4288*2)   -- later reused for R
  //   [70,254,592 .. 107,577,344)  Wt2 (4352*4288*2)
  //   [107,577,344 .. 178,880,512) Q  (8192*4352*2)
  // R (8192*4352*2 = 71,303,168) is built AFTER gemm1 at offset 0.
  char* ws = (char*)d_ws;
  __hip_bfloat16* P = (__hip_bfloat16*)(ws);
  __hip_bfloat16* Wt2 = (__hip_bfloat16*)(ws + 70254592ULL);
  __hip_bfloat16* Q = (__hip_bfloat16*)(ws + 107577344ULL);
  __hip_bfloat16* R = (__hip_bfloat16*)(ws);  // reuses P/Wt2 region

  // 1) zero Wt2 (covers pad rows/cols; real entries overwritten next)
  zero_kernel<<<2048, 256, 0, stream>>>((float4*)Wt2, (long)DP * KP * 2 / 16);
  // 2) transpose+cast W
  build_wt2<<<dim3(65, 65), 256, 0, stream>>>(W, Wt2);
  // 3) P
  build_p<<<NROW, 256, 0, stream>>>(layer1, h1, P, KP);
  // 4) Q = P @ Wt2 (NT): M=8192, N=4352, K=4288
  gemm_nt<1><<<dim3(DP / 128, NROW / 128, 1), 256, 0, stream>>>(
      P, Wt2, Q, KP, KP, KP, DP, 0, 0, 0);
  // 5) R (over the now-dead P/Wt2 region)
  build_p<<<NROW, 256, 0, stream>>>(layer2, h2, R, DP);
  // 6) out_n = Q_n @ R_n^T: M=N=1024, K=4352, batched over n=8
  gemm_nt<0><<<dim3(1024 / 128, 1024 / 128, 8), 256, 0, stream>>>(
      Q, R, out, DP, DP, DP, 1024, 1024L * DP, 1024L * DP, 1024L * 1024);
}